// Round 1
// baseline (3189.903 us; speedup 1.0000x reference)
//
#include <hip/hip_runtime.h>

#define NNODES 20000
#define NEDGES 320000
#define HID 128
#define NL 4

constexpr int NH = NNODES * HID;

// ---------------------------------------------------------------- embed
// x[n][j] = h[n][0]*ew[0][j] + h[n][1]*ew[1][j] + eb[j]
__global__ __launch_bounds__(256) void k_embed(const float* __restrict__ h,
    const float* __restrict__ ew, const float* __restrict__ eb, float* __restrict__ x)
{
    int i = blockIdx.x * 256 + threadIdx.x;          // exactly NH threads
    int nrow = i >> 7, j = i & 127;
    x[i] = fmaf(h[nrow * 2], ew[j], fmaf(h[nrow * 2 + 1], ew[HID + j], eb[j]));
}

// ------------------------------------------------------- scatter (segment_sum)
__global__ __launch_bounds__(256) void k_scatter_init(const float* __restrict__ x,
    float* __restrict__ t, const float* __restrict__ eps, int layer)
{
    int i = blockIdx.x * 256 + threadIdx.x;
    t[i] = (1.0f + eps[layer]) * x[i];
}

__global__ __launch_bounds__(256) void k_scatter_add(const float* __restrict__ x,
    const int* __restrict__ src, const int* __restrict__ dst, float* __restrict__ t)
{
    int tid = blockIdx.x * 256 + threadIdx.x;        // E*32 threads exactly
    int e = tid >> 5, l = tid & 31;
    int s = src[e], d = dst[e];
    const float4 v = *reinterpret_cast<const float4*>(x + (size_t)s * HID + l * 4);
    float* p = t + (size_t)d * HID + l * 4;
    atomicAdd(p + 0, v.x);
    atomicAdd(p + 1, v.y);
    atomicAdd(p + 2, v.z);
    atomicAdd(p + 3, v.w);
}

// ---------------------------------------------------------------- GEMM
// C[N,128] = X[N,128] @ W[128,128] (+ bias). 64 rows/block, thread tile 4x8.
#define XPAD 132
__global__ __launch_bounds__(256) void k_gemm(const float* __restrict__ X,
    const float* __restrict__ W, const float* __restrict__ bias,
    float* __restrict__ Cm, int hasbias)
{
    __shared__ float Xs[64][XPAD];
    const int tid = threadIdx.x;
    const int br = blockIdx.x * 64;
    #pragma unroll
    for (int it = 0; it < 8; ++it) {
        int f = tid + it * 256;
        int r = f >> 5;
        int kq = (f & 31) << 2;
        int row = br + r;
        float4 v = make_float4(0.f, 0.f, 0.f, 0.f);
        if (row < NNODES) v = *reinterpret_cast<const float4*>(X + (size_t)row * HID + kq);
        *reinterpret_cast<float4*>(&Xs[r][kq]) = v;
    }
    __syncthreads();
    const int j0 = (tid & 15) * 8;
    const int r0 = (tid >> 4) * 4;
    float acc[4][8];
    #pragma unroll
    for (int r = 0; r < 4; ++r)
        #pragma unroll
        for (int c = 0; c < 8; ++c) acc[r][c] = 0.f;

    for (int k = 0; k < 128; ++k) {
        const float4 wa = *reinterpret_cast<const float4*>(W + k * HID + j0);
        const float4 wb = *reinterpret_cast<const float4*>(W + k * HID + j0 + 4);
        const float w[8] = {wa.x, wa.y, wa.z, wa.w, wb.x, wb.y, wb.z, wb.w};
        #pragma unroll
        for (int r = 0; r < 4; ++r) {
            const float xv = Xs[r0 + r][k];
            #pragma unroll
            for (int c = 0; c < 8; ++c) acc[r][c] = fmaf(xv, w[c], acc[r][c]);
        }
    }
    float bv[8];
    #pragma unroll
    for (int c = 0; c < 8; ++c) bv[c] = hasbias ? bias[j0 + c] : 0.f;
    #pragma unroll
    for (int r = 0; r < 4; ++r) {
        int row = br + r0 + r;
        if (row < NNODES) {
            float4 o0 = make_float4(acc[r][0] + bv[0], acc[r][1] + bv[1],
                                    acc[r][2] + bv[2], acc[r][3] + bv[3]);
            float4 o1 = make_float4(acc[r][4] + bv[4], acc[r][5] + bv[5],
                                    acc[r][6] + bv[6], acc[r][7] + bv[7]);
            *reinterpret_cast<float4*>(Cm + (size_t)row * HID + j0) = o0;
            *reinterpret_cast<float4*>(Cm + (size_t)row * HID + j0 + 4) = o1;
        }
    }
}

// Dual GEMM for prediction heads: A = X@W1[0:128] + b1 ; B = X@W1[128:256]
__global__ __launch_bounds__(256) void k_gemm_head(const float* __restrict__ X,
    const float* __restrict__ W1, const float* __restrict__ b1,
    float* __restrict__ A, float* __restrict__ Bm)
{
    __shared__ float Xs[64][XPAD];
    const int tid = threadIdx.x;
    const int br = blockIdx.x * 64;
    #pragma unroll
    for (int it = 0; it < 8; ++it) {
        int f = tid + it * 256;
        int r = f >> 5;
        int kq = (f & 31) << 2;
        int row = br + r;
        float4 v = make_float4(0.f, 0.f, 0.f, 0.f);
        if (row < NNODES) v = *reinterpret_cast<const float4*>(X + (size_t)row * HID + kq);
        *reinterpret_cast<float4*>(&Xs[r][kq]) = v;
    }
    __syncthreads();
    const int j0 = (tid & 15) * 8;
    const int r0 = (tid >> 4) * 4;
    float accA[4][8], accB[4][8];
    #pragma unroll
    for (int r = 0; r < 4; ++r)
        #pragma unroll
        for (int c = 0; c < 8; ++c) { accA[r][c] = 0.f; accB[r][c] = 0.f; }

    for (int k = 0; k < 128; ++k) {
        const float4 wa0 = *reinterpret_cast<const float4*>(W1 + k * HID + j0);
        const float4 wa1 = *reinterpret_cast<const float4*>(W1 + k * HID + j0 + 4);
        const float4 wb0 = *reinterpret_cast<const float4*>(W1 + (HID + k) * HID + j0);
        const float4 wb1 = *reinterpret_cast<const float4*>(W1 + (HID + k) * HID + j0 + 4);
        const float wa[8] = {wa0.x, wa0.y, wa0.z, wa0.w, wa1.x, wa1.y, wa1.z, wa1.w};
        const float wb[8] = {wb0.x, wb0.y, wb0.z, wb0.w, wb1.x, wb1.y, wb1.z, wb1.w};
        #pragma unroll
        for (int r = 0; r < 4; ++r) {
            const float xv = Xs[r0 + r][k];
            #pragma unroll
            for (int c = 0; c < 8; ++c) {
                accA[r][c] = fmaf(xv, wa[c], accA[r][c]);
                accB[r][c] = fmaf(xv, wb[c], accB[r][c]);
            }
        }
    }
    #pragma unroll
    for (int r = 0; r < 4; ++r) {
        int row = br + r0 + r;
        if (row < NNODES) {
            #pragma unroll
            for (int c = 0; c < 8; ++c) {
                A[(size_t)row * HID + j0 + c]  = accA[r][c] + b1[j0 + c];
                Bm[(size_t)row * HID + j0 + c] = accB[r][c];
            }
        }
    }
}

// ---------------------------------------------------------------- batchnorm
__global__ __launch_bounds__(256) void k_bnstats(const float* __restrict__ v,
    float* __restrict__ sums)
{
    int j = threadIdx.x & 127;
    int half = threadIdx.x >> 7;
    int rbase = blockIdx.x * 128;
    int rend = min(rbase + 128, NNODES);
    float s = 0.f, q = 0.f;
    for (int r = rbase + half; r < rend; r += 2) {
        float val = v[(size_t)r * HID + j];
        s += val;
        q = fmaf(val, val, q);
    }
    atomicAdd(&sums[j], s);
    atomicAdd(&sums[HID + j], q);
}

__global__ void k_bnfin(const float* __restrict__ sums, const float* __restrict__ g,
    const float* __restrict__ b, float* __restrict__ ac)
{
    int j = threadIdx.x;   // 128 threads
    const float inv = 1.0f / (float)NNODES;
    float m = sums[j] * inv;
    float var = fmaf(-m, m, sums[HID + j] * inv);
    float a = g[j] * rsqrtf(var + 1e-5f);
    ac[j] = a;
    ac[HID + j] = fmaf(-m, a, b[j]);
}

// o = relu(a*v + c) (+ resid). resid==nullptr -> plain.
__global__ __launch_bounds__(256) void k_bnapply(const float* __restrict__ v,
    const float* __restrict__ ac, float* __restrict__ o, const float* __restrict__ resid)
{
    int i = blockIdx.x * 256 + threadIdx.x;
    int j = i & 127;
    float y = fmaxf(fmaf(ac[j], v[i], ac[HID + j]), 0.f);
    o[i] = resid ? resid[i] + y : y;
}

// ---------------------------------------------------------------- edge head
// score[e][c] (+)= relu(A[src]+B[dst]) . W2[:,c] + b2[c] ; 32 lanes/edge
__global__ __launch_bounds__(256) void k_edge(const float* __restrict__ A,
    const float* __restrict__ Bm, const int* __restrict__ src, const int* __restrict__ dst,
    const float* __restrict__ w2, const float* __restrict__ b2,
    float* __restrict__ out, int accumulate)
{
    int tid = blockIdx.x * 256 + threadIdx.x;        // E*32 threads exactly
    int e = tid >> 5, l = tid & 31;
    int s = src[e], d = dst[e];
    const float4 a = *reinterpret_cast<const float4*>(A + (size_t)s * HID + l * 4);
    const float4 b = *reinterpret_cast<const float4*>(Bm + (size_t)d * HID + l * 4);
    float z0 = fmaxf(a.x + b.x, 0.f);
    float z1 = fmaxf(a.y + b.y, 0.f);
    float z2 = fmaxf(a.z + b.z, 0.f);
    float z3 = fmaxf(a.w + b.w, 0.f);
    const float4 w01 = *reinterpret_cast<const float4*>(w2 + l * 8);
    const float4 w23 = *reinterpret_cast<const float4*>(w2 + l * 8 + 4);
    float s0 = z0 * w01.x + z1 * w01.z + z2 * w23.x + z3 * w23.z;
    float s1 = z0 * w01.y + z1 * w01.w + z2 * w23.y + z3 * w23.w;
    #pragma unroll
    for (int m = 16; m >= 1; m >>= 1) {
        s0 += __shfl_xor(s0, m);
        s1 += __shfl_xor(s1, m);
    }
    if (l == 0) {
        float o0 = s0 + b2[0], o1 = s1 + b2[1];
        if (accumulate) {
            out[e * 2 + 0] += o0;
            out[e * 2 + 1] += o1;
        } else {
            out[e * 2 + 0] = o0;
            out[e * 2 + 1] = o1;
        }
    }
}

// ---------------------------------------------------------------- launch
extern "C" void kernel_launch(void* const* d_in, const int* in_sizes, int n_in,
                              void* d_out, int out_size, void* d_ws, size_t ws_size,
                              hipStream_t stream)
{
    const float* h        = (const float*)d_in[0];
    const int*   src      = (const int*)d_in[1];
    const int*   dst      = (const int*)d_in[2];
    const float* emb_w    = (const float*)d_in[3];
    const float* emb_b    = (const float*)d_in[4];
    const float* eps      = (const float*)d_in[5];
    const float* mlp_w1   = (const float*)d_in[6];
    const float* mlp_b1   = (const float*)d_in[7];
    const float* mlp_bn_g = (const float*)d_in[8];
    const float* mlp_bn_b = (const float*)d_in[9];
    const float* mlp_w2   = (const float*)d_in[10];
    const float* mlp_b2   = (const float*)d_in[11];
    const float* app_bn_g = (const float*)d_in[12];
    const float* app_bn_b = (const float*)d_in[13];
    const float* gin_bn_g = (const float*)d_in[14];
    const float* gin_bn_b = (const float*)d_in[15];
    const float* pred_w1  = (const float*)d_in[16];
    const float* pred_b1  = (const float*)d_in[17];
    const float* pred_w2  = (const float*)d_in[18];
    const float* pred_b2  = (const float*)d_in[19];
    float* out = (float*)d_out;

    float* ws   = (float*)d_ws;
    float* x    = ws;                 // [N,128]
    float* tmp1 = ws + NH;            // [N,128]
    float* tmp2 = ws + 2 * (size_t)NH;// [N,128]
    float* sums = ws + 3 * (size_t)NH;// [256]
    float* ac   = sums + 256;         // [256]

    const int NB = NH / 256;                    // 10000
    const int EW = NEDGES * 32 / 256;           // 40000
    const int GB = (NNODES + 63) / 64;          // 313
    const int SB = (NNODES + 127) / 128;        // 157

    k_embed<<<NB, 256, 0, stream>>>(h, emb_w, emb_b, x);

    // head 0
    k_gemm_head<<<GB, 256, 0, stream>>>(x, pred_w1, pred_b1, tmp1, tmp2);
    k_edge<<<EW, 256, 0, stream>>>(tmp1, tmp2, src, dst, pred_w2, pred_b2, out, 0);

    for (int i = 0; i < NL; ++i) {
        // z = (1+eps)*x + segment_sum(x[src], dst)
        k_scatter_init<<<NB, 256, 0, stream>>>(x, tmp1, eps, i);
        k_scatter_add<<<EW, 256, 0, stream>>>(x, src, dst, tmp1);

        // u = z @ mlp_w1 + b1 ; BN ; relu
        k_gemm<<<GB, 256, 0, stream>>>(tmp1, mlp_w1 + (size_t)i * HID * HID,
                                       mlp_b1 + i * HID, tmp2, 1);
        hipMemsetAsync(sums, 0, 256 * sizeof(float), stream);
        k_bnstats<<<SB, 256, 0, stream>>>(tmp2, sums);
        k_bnfin<<<1, 128, 0, stream>>>(sums, mlp_bn_g + i * HID, mlp_bn_b + i * HID, ac);
        k_bnapply<<<NB, 256, 0, stream>>>(tmp2, ac, tmp2, nullptr);

        // v = u @ mlp_w2 + b2 ; app BN ; relu
        k_gemm<<<GB, 256, 0, stream>>>(tmp2, mlp_w2 + (size_t)i * HID * HID,
                                       mlp_b2 + i * HID, tmp1, 1);
        hipMemsetAsync(sums, 0, 256 * sizeof(float), stream);
        k_bnstats<<<SB, 256, 0, stream>>>(tmp1, sums);
        k_bnfin<<<1, 128, 0, stream>>>(sums, app_bn_g + i * HID, app_bn_b + i * HID, ac);
        k_bnapply<<<NB, 256, 0, stream>>>(tmp1, ac, tmp1, nullptr);

        // gin BN ; relu ; residual
        hipMemsetAsync(sums, 0, 256 * sizeof(float), stream);
        k_bnstats<<<SB, 256, 0, stream>>>(tmp1, sums);
        k_bnfin<<<1, 128, 0, stream>>>(sums, gin_bn_g + i * HID, gin_bn_b + i * HID, ac);
        k_bnapply<<<NB, 256, 0, stream>>>(tmp1, ac, x, x);   // x = x + relu(BN(v))

        // head i+1
        k_gemm_head<<<GB, 256, 0, stream>>>(x, pred_w1 + (size_t)(i + 1) * 256 * HID,
                                            pred_b1 + (i + 1) * HID, tmp1, tmp2);
        k_edge<<<EW, 256, 0, stream>>>(tmp1, tmp2, src, dst,
                                       pred_w2 + (i + 1) * HID * 2,
                                       pred_b2 + (i + 1) * 2, out, 1);
    }
}

// Round 2
// 1173.075 us; speedup vs baseline: 2.7193x; 2.7193x over previous
//
#include <hip/hip_runtime.h>

#define NNODES 20000
#define NEDGES 320000
#define HID 128
#define NL 4

constexpr int NH = NNODES * HID;

// ---------------------------------------------------------------- embed
__global__ __launch_bounds__(256) void k_embed(const float* __restrict__ h,
    const float* __restrict__ ew, const float* __restrict__ eb, float* __restrict__ x)
{
    int i = blockIdx.x * 256 + threadIdx.x;          // exactly NH threads
    int nrow = i >> 7, j = i & 127;
    x[i] = fmaf(h[nrow * 2], ew[j], fmaf(h[nrow * 2 + 1], ew[HID + j], eb[j]));
}

// ---------------------------------------------------------------- CSR build
__global__ __launch_bounds__(256) void k_hist(const int* __restrict__ dst,
    int* __restrict__ deg)
{
    int e = blockIdx.x * 256 + threadIdx.x;          // exactly NEDGES threads
    atomicAdd(&deg[dst[e]], 1);
}

__global__ __launch_bounds__(1024) void k_scan(const int* __restrict__ deg,
    int* __restrict__ off)
{
    __shared__ int part[1024];
    const int t = threadIdx.x;
    const int lo = t * 20, hi = min(lo + 20, NNODES);   // 1024*20 = 20480 >= 20000
    int s = 0;
    for (int i = lo; i < hi; ++i) s += deg[i];
    part[t] = s;
    __syncthreads();
    for (int d = 1; d < 1024; d <<= 1) {
        int v = (t >= d) ? part[t - d] : 0;
        __syncthreads();
        part[t] += v;
        __syncthreads();
    }
    int base = part[t] - s;                          // exclusive prefix
    for (int i = lo; i < hi; ++i) { off[i] = base; base += deg[i]; }
}

// fill: bump off (exclusive->inclusive) and store src as u16
__global__ __launch_bounds__(256) void k_fill(const int* __restrict__ src,
    const int* __restrict__ dst, int* __restrict__ off, unsigned short* __restrict__ eidx)
{
    int e = blockIdx.x * 256 + threadIdx.x;          // exactly NEDGES threads
    int p = atomicAdd(&off[dst[e]], 1);
    eidx[p] = (unsigned short)src[e];
}

// ------------------------------------------- pull-mode aggregate (no atomics)
// t[n] = (1+eps)*x[n] + sum_{e in in(n)} x[eidx[e]]
// post-fill: off[n] = inclusive prefix; start = off[n-1] (0 for n=0)
__global__ __launch_bounds__(256) void k_gather(const float* __restrict__ x,
    const int* __restrict__ off, const unsigned short* __restrict__ eidx,
    const float* __restrict__ eps, int layer, float* __restrict__ t)
{
    int tid = blockIdx.x * 256 + threadIdx.x;        // NNODES*32 threads exactly
    int n = tid >> 5, l = tid & 31;
    int start = (n == 0) ? 0 : off[n - 1];
    int end = off[n];
    const float4* xr = reinterpret_cast<const float4*>(x);
    float4 a = xr[(size_t)n * 32 + l];
    float e1 = 1.0f + eps[layer];
    float4 acc = make_float4(a.x * e1, a.y * e1, a.z * e1, a.w * e1);
    for (int e = start; e < end; ++e) {
        int s = eidx[e];
        float4 v = xr[(size_t)s * 32 + l];
        acc.x += v.x; acc.y += v.y; acc.z += v.z; acc.w += v.w;
    }
    reinterpret_cast<float4*>(t)[(size_t)n * 32 + l] = acc;
}

// ---------------------------------------------------------------- GEMM
#define XPAD 132
__global__ __launch_bounds__(256) void k_gemm(const float* __restrict__ X,
    const float* __restrict__ W, const float* __restrict__ bias,
    float* __restrict__ Cm, int hasbias)
{
    __shared__ float Xs[64][XPAD];
    const int tid = threadIdx.x;
    const int br = blockIdx.x * 64;
    #pragma unroll
    for (int it = 0; it < 8; ++it) {
        int f = tid + it * 256;
        int r = f >> 5;
        int kq = (f & 31) << 2;
        int row = br + r;
        float4 v = make_float4(0.f, 0.f, 0.f, 0.f);
        if (row < NNODES) v = *reinterpret_cast<const float4*>(X + (size_t)row * HID + kq);
        *reinterpret_cast<float4*>(&Xs[r][kq]) = v;
    }
    __syncthreads();
    const int j0 = (tid & 15) * 8;
    const int r0 = (tid >> 4) * 4;
    float acc[4][8];
    #pragma unroll
    for (int r = 0; r < 4; ++r)
        #pragma unroll
        for (int c = 0; c < 8; ++c) acc[r][c] = 0.f;

    for (int k = 0; k < 128; ++k) {
        const float4 wa = *reinterpret_cast<const float4*>(W + k * HID + j0);
        const float4 wb = *reinterpret_cast<const float4*>(W + k * HID + j0 + 4);
        const float w[8] = {wa.x, wa.y, wa.z, wa.w, wb.x, wb.y, wb.z, wb.w};
        #pragma unroll
        for (int r = 0; r < 4; ++r) {
            const float xv = Xs[r0 + r][k];
            #pragma unroll
            for (int c = 0; c < 8; ++c) acc[r][c] = fmaf(xv, w[c], acc[r][c]);
        }
    }
    float bv[8];
    #pragma unroll
    for (int c = 0; c < 8; ++c) bv[c] = hasbias ? bias[j0 + c] : 0.f;
    #pragma unroll
    for (int r = 0; r < 4; ++r) {
        int row = br + r0 + r;
        if (row < NNODES) {
            float4 o0 = make_float4(acc[r][0] + bv[0], acc[r][1] + bv[1],
                                    acc[r][2] + bv[2], acc[r][3] + bv[3]);
            float4 o1 = make_float4(acc[r][4] + bv[4], acc[r][5] + bv[5],
                                    acc[r][6] + bv[6], acc[r][7] + bv[7]);
            *reinterpret_cast<float4*>(Cm + (size_t)row * HID + j0) = o0;
            *reinterpret_cast<float4*>(Cm + (size_t)row * HID + j0 + 4) = o1;
        }
    }
}

// Dual GEMM for prediction heads: A = X@W1[0:128] + b1 ; B = X@W1[128:256]
__global__ __launch_bounds__(256) void k_gemm_head(const float* __restrict__ X,
    const float* __restrict__ W1, const float* __restrict__ b1,
    float* __restrict__ A, float* __restrict__ Bm)
{
    __shared__ float Xs[64][XPAD];
    const int tid = threadIdx.x;
    const int br = blockIdx.x * 64;
    #pragma unroll
    for (int it = 0; it < 8; ++it) {
        int f = tid + it * 256;
        int r = f >> 5;
        int kq = (f & 31) << 2;
        int row = br + r;
        float4 v = make_float4(0.f, 0.f, 0.f, 0.f);
        if (row < NNODES) v = *reinterpret_cast<const float4*>(X + (size_t)row * HID + kq);
        *reinterpret_cast<float4*>(&Xs[r][kq]) = v;
    }
    __syncthreads();
    const int j0 = (tid & 15) * 8;
    const int r0 = (tid >> 4) * 4;
    float accA[4][8], accB[4][8];
    #pragma unroll
    for (int r = 0; r < 4; ++r)
        #pragma unroll
        for (int c = 0; c < 8; ++c) { accA[r][c] = 0.f; accB[r][c] = 0.f; }

    for (int k = 0; k < 128; ++k) {
        const float4 wa0 = *reinterpret_cast<const float4*>(W1 + k * HID + j0);
        const float4 wa1 = *reinterpret_cast<const float4*>(W1 + k * HID + j0 + 4);
        const float4 wb0 = *reinterpret_cast<const float4*>(W1 + (HID + k) * HID + j0);
        const float4 wb1 = *reinterpret_cast<const float4*>(W1 + (HID + k) * HID + j0 + 4);
        const float wa[8] = {wa0.x, wa0.y, wa0.z, wa0.w, wa1.x, wa1.y, wa1.z, wa1.w};
        const float wb[8] = {wb0.x, wb0.y, wb0.z, wb0.w, wb1.x, wb1.y, wb1.z, wb1.w};
        #pragma unroll
        for (int r = 0; r < 4; ++r) {
            const float xv = Xs[r0 + r][k];
            #pragma unroll
            for (int c = 0; c < 8; ++c) {
                accA[r][c] = fmaf(xv, wa[c], accA[r][c]);
                accB[r][c] = fmaf(xv, wb[c], accB[r][c]);
            }
        }
    }
    #pragma unroll
    for (int r = 0; r < 4; ++r) {
        int row = br + r0 + r;
        if (row < NNODES) {
            #pragma unroll
            for (int c = 0; c < 8; ++c) {
                A[(size_t)row * HID + j0 + c]  = accA[r][c] + b1[j0 + c];
                Bm[(size_t)row * HID + j0 + c] = accB[r][c];
            }
        }
    }
}

// ---------------------------------------------------------------- batchnorm
__global__ __launch_bounds__(256) void k_bnstats(const float* __restrict__ v,
    float* __restrict__ sums)
{
    int j = threadIdx.x & 127;
    int half = threadIdx.x >> 7;
    int rbase = blockIdx.x * 128;
    int rend = min(rbase + 128, NNODES);
    float s = 0.f, q = 0.f;
    for (int r = rbase + half; r < rend; r += 2) {
        float val = v[(size_t)r * HID + j];
        s += val;
        q = fmaf(val, val, q);
    }
    atomicAdd(&sums[j], s);
    atomicAdd(&sums[HID + j], q);
}

__global__ void k_bnfin(const float* __restrict__ sums, const float* __restrict__ g,
    const float* __restrict__ b, float* __restrict__ ac)
{
    int j = threadIdx.x;   // 128 threads
    const float inv = 1.0f / (float)NNODES;
    float m = sums[j] * inv;
    float var = fmaf(-m, m, sums[HID + j] * inv);
    float a = g[j] * rsqrtf(var + 1e-5f);
    ac[j] = a;
    ac[HID + j] = fmaf(-m, a, b[j]);
}

__global__ __launch_bounds__(256) void k_bnapply(const float* __restrict__ v,
    const float* __restrict__ ac, float* __restrict__ o, const float* __restrict__ resid)
{
    int i = blockIdx.x * 256 + threadIdx.x;
    int j = i & 127;
    float y = fmaxf(fmaf(ac[j], v[i], ac[HID + j]), 0.f);
    o[i] = resid ? resid[i] + y : y;
}

// ---------------------------------------------------------------- edge head
__global__ __launch_bounds__(256) void k_edge(const float* __restrict__ A,
    const float* __restrict__ Bm, const int* __restrict__ src, const int* __restrict__ dst,
    const float* __restrict__ w2, const float* __restrict__ b2,
    float* __restrict__ out, int accumulate)
{
    int tid = blockIdx.x * 256 + threadIdx.x;        // E*32 threads exactly
    int e = tid >> 5, l = tid & 31;
    int s = src[e], d = dst[e];
    const float4 a = *reinterpret_cast<const float4*>(A + (size_t)s * HID + l * 4);
    const float4 b = *reinterpret_cast<const float4*>(Bm + (size_t)d * HID + l * 4);
    float z0 = fmaxf(a.x + b.x, 0.f);
    float z1 = fmaxf(a.y + b.y, 0.f);
    float z2 = fmaxf(a.z + b.z, 0.f);
    float z3 = fmaxf(a.w + b.w, 0.f);
    const float4 w01 = *reinterpret_cast<const float4*>(w2 + l * 8);
    const float4 w23 = *reinterpret_cast<const float4*>(w2 + l * 8 + 4);
    float s0 = z0 * w01.x + z1 * w01.z + z2 * w23.x + z3 * w23.z;
    float s1 = z0 * w01.y + z1 * w01.w + z2 * w23.y + z3 * w23.w;
    #pragma unroll
    for (int m = 16; m >= 1; m >>= 1) {
        s0 += __shfl_xor(s0, m);
        s1 += __shfl_xor(s1, m);
    }
    if (l == 0) {
        float o0 = s0 + b2[0], o1 = s1 + b2[1];
        if (accumulate) {
            out[e * 2 + 0] += o0;
            out[e * 2 + 1] += o1;
        } else {
            out[e * 2 + 0] = o0;
            out[e * 2 + 1] = o1;
        }
    }
}

// ---------------------------------------------------------------- launch
extern "C" void kernel_launch(void* const* d_in, const int* in_sizes, int n_in,
                              void* d_out, int out_size, void* d_ws, size_t ws_size,
                              hipStream_t stream)
{
    const float* h        = (const float*)d_in[0];
    const int*   src      = (const int*)d_in[1];
    const int*   dst      = (const int*)d_in[2];
    const float* emb_w    = (const float*)d_in[3];
    const float* emb_b    = (const float*)d_in[4];
    const float* eps      = (const float*)d_in[5];
    const float* mlp_w1   = (const float*)d_in[6];
    const float* mlp_b1   = (const float*)d_in[7];
    const float* mlp_bn_g = (const float*)d_in[8];
    const float* mlp_bn_b = (const float*)d_in[9];
    const float* mlp_w2   = (const float*)d_in[10];
    const float* mlp_b2   = (const float*)d_in[11];
    const float* app_bn_g = (const float*)d_in[12];
    const float* app_bn_b = (const float*)d_in[13];
    const float* gin_bn_g = (const float*)d_in[14];
    const float* gin_bn_b = (const float*)d_in[15];
    const float* pred_w1  = (const float*)d_in[16];
    const float* pred_b1  = (const float*)d_in[17];
    const float* pred_w2  = (const float*)d_in[18];
    const float* pred_b2  = (const float*)d_in[19];
    float* out = (float*)d_out;

    float* ws   = (float*)d_ws;
    float* x    = ws;                       // [N,128]
    float* tmp1 = ws + NH;                  // [N,128]
    float* tmp2 = ws + 2 * (size_t)NH;      // [N,128]
    float* sums = ws + 3 * (size_t)NH;      // [256]
    float* ac   = sums + 256;               // [256]
    int*   off  = (int*)(ac + 256);         // [N]
    int*   deg  = off + NNODES;             // [N]
    unsigned short* eidx = (unsigned short*)(deg + NNODES);  // [E]

    const int NB = NH / 256;                    // 10000
    const int EB = NEDGES / 256;                // 1250
    const int EW = NEDGES * 32 / 256;           // 40000
    const int GB = (NNODES + 63) / 64;          // 313
    const int SB = (NNODES + 127) / 128;        // 157
    const int AGB = NNODES * 32 / 256;          // 2500

    // ---- CSR build (once; graph static across layers)
    hipMemsetAsync(deg, 0, NNODES * sizeof(int), stream);
    k_hist<<<EB, 256, 0, stream>>>(dst, deg);
    k_scan<<<1, 1024, 0, stream>>>(deg, off);
    k_fill<<<EB, 256, 0, stream>>>(src, dst, off, eidx);  // off -> inclusive prefix

    k_embed<<<NB, 256, 0, stream>>>(h, emb_w, emb_b, x);

    // head 0
    k_gemm_head<<<GB, 256, 0, stream>>>(x, pred_w1, pred_b1, tmp1, tmp2);
    k_edge<<<EW, 256, 0, stream>>>(tmp1, tmp2, src, dst, pred_w2, pred_b2, out, 0);

    for (int i = 0; i < NL; ++i) {
        // t = (1+eps)*x + segment_sum(x[src], dst)   (pull-mode, no atomics)
        k_gather<<<AGB, 256, 0, stream>>>(x, off, eidx, eps, i, tmp1);

        // u = t @ mlp_w1 + b1 ; BN ; relu
        k_gemm<<<GB, 256, 0, stream>>>(tmp1, mlp_w1 + (size_t)i * HID * HID,
                                       mlp_b1 + i * HID, tmp2, 1);
        hipMemsetAsync(sums, 0, 256 * sizeof(float), stream);
        k_bnstats<<<SB, 256, 0, stream>>>(tmp2, sums);
        k_bnfin<<<1, 128, 0, stream>>>(sums, mlp_bn_g + i * HID, mlp_bn_b + i * HID, ac);
        k_bnapply<<<NB, 256, 0, stream>>>(tmp2, ac, tmp2, nullptr);

        // v = u @ mlp_w2 + b2 ; app BN ; relu
        k_gemm<<<GB, 256, 0, stream>>>(tmp2, mlp_w2 + (size_t)i * HID * HID,
                                       mlp_b2 + i * HID, tmp1, 1);
        hipMemsetAsync(sums, 0, 256 * sizeof(float), stream);
        k_bnstats<<<SB, 256, 0, stream>>>(tmp1, sums);
        k_bnfin<<<1, 128, 0, stream>>>(sums, app_bn_g + i * HID, app_bn_b + i * HID, ac);
        k_bnapply<<<NB, 256, 0, stream>>>(tmp1, ac, tmp1, nullptr);

        // gin BN ; relu ; residual
        hipMemsetAsync(sums, 0, 256 * sizeof(float), stream);
        k_bnstats<<<SB, 256, 0, stream>>>(tmp1, sums);
        k_bnfin<<<1, 128, 0, stream>>>(sums, gin_bn_g + i * HID, gin_bn_b + i * HID, ac);
        k_bnapply<<<NB, 256, 0, stream>>>(tmp1, ac, x, x);   // x = x + relu(BN(v))

        // head i+1
        k_gemm_head<<<GB, 256, 0, stream>>>(x, pred_w1 + (size_t)(i + 1) * 256 * HID,
                                            pred_b1 + (i + 1) * HID, tmp1, tmp2);
        k_edge<<<EW, 256, 0, stream>>>(tmp1, tmp2, src, dst,
                                       pred_w2 + (i + 1) * HID * 2,
                                       pred_b2 + (i + 1) * 2, out, 1);
    }
}